// Round 1
// baseline (220.001 us; speedup 1.0000x reference)
//
#include <hip/hip_runtime.h>
#include <cstdint>
#include <cstddef>

// ---------------------------------------------------------------------------
// Conv2d 3x3 s1 p1 on 16-bit fixed-point (12 frac bits) quantized operands.
// x: (32,128,56,56) f32   w: (256,128,3,3) f32   out: (32,256,56,56) f32
// Implicit GEMM M=256, N=100352, K=1152.
// THIS VERSION: 256x256 tile, BK=64, 512 thr / 8 waves, 8-phase schedule with
// counted vmcnt (T3+T4) + setprio (T5), XOR-8 chunk swizzle kept from prior
// version (proven conflict-free), XCD-aware block swizzle (392 = 8*49).
// ---------------------------------------------------------------------------

typedef __attribute__((ext_vector_type(8))) short short8;
typedef __attribute__((ext_vector_type(4))) float floatx4;

#define NIMG 32
#define CIN  128
#define HW   56
#define KOUT 256
#define HP   58                                   // padded H/W
#define XPAD_ELEMS ((size_t)NIMG * HP * HP * CIN) // 13,778,944
#define WT_OFF_BYTES (XPAD_ELEMS * 2)             // 27,557,888 (256B aligned)
#define KK 1152

__device__ __forceinline__ uint16_t quant_bf16(float v) {
    // round-half-even to 12 frac bits, clip to int16 range, then RNE to bf16
    float q = rintf(v * 4096.0f);
    q = fminf(fmaxf(q, -32768.0f), 32767.0f) * (1.0f / 4096.0f);
    union { float f; uint32_t u; } cv; cv.f = q;
    uint32_t u = cv.u;
    return (uint16_t)((u + 0x7fffu + ((u >> 16) & 1u)) >> 16);
}

// ---- transform x: NCHW f32 -> padded NHWC bf16 [32][58][58][128] ----------
__global__ __launch_bounds__(256) void quant_pad_x(const float* __restrict__ x,
                                                   uint16_t* __restrict__ xp) {
    const int b = blockIdx.x;            // one padded row (n, hp) each
    const int n = b / HP, hp = b - n * HP;
    uint16_t* row = xp + (size_t)(n * HP + hp) * HP * CIN;

    if (hp == 0 || hp == HP - 1) {       // top/bottom pad row: all zeros
        uint4 z{0, 0, 0, 0};
        uint4* d = (uint4*)row;
        for (int t = threadIdx.x; t < HP * CIN * 2 / 16; t += 256) d[t] = z;
        return;
    }
    const int h = hp - 1;
    __shared__ uint16_t tile[HW * 130];  // [w][c], +2 pad breaks bank conflicts
    const float* src = x + (size_t)n * CIN * HW * HW + (size_t)h * HW;
    for (int t = threadIdx.x; t < CIN * 14; t += 256) {      // float4 loads
        int c = t / 14, w4 = t - c * 14;
        float4 v = *(const float4*)(src + (size_t)c * (HW * HW) + w4 * 4);
        int base = (w4 * 4) * 130 + c;
        tile[base]       = quant_bf16(v.x);
        tile[base + 130] = quant_bf16(v.y);
        tile[base + 260] = quant_bf16(v.z);
        tile[base + 390] = quant_bf16(v.w);
    }
    __syncthreads();
    if (threadIdx.x < 32) {              // zero left/right pad pixels
        uint4 z{0, 0, 0, 0};
        if (threadIdx.x < 16) ((uint4*)row)[threadIdx.x] = z;
        else ((uint4*)(row + 57 * CIN))[threadIdx.x - 16] = z;
    }
    uint2* dst = (uint2*)(row + CIN);    // interior cols 1..56, 8B stores
    for (int t = threadIdx.x; t < (HW * CIN) / 4; t += 256) {
        int w = t >> 5, c4 = (t & 31) * 4;
        uint32_t a = tile[w * 130 + c4]     | ((uint32_t)tile[w * 130 + c4 + 1] << 16);
        uint32_t c = tile[w * 130 + c4 + 2] | ((uint32_t)tile[w * 130 + c4 + 3] << 16);
        dst[t] = make_uint2(a, c);
    }
}

// ---- transform w: OIHW f32 -> Wt[k][tap*128+c] bf16 ------------------------
__global__ __launch_bounds__(256) void quant_w(const float* __restrict__ w,
                                               uint16_t* __restrict__ wt) {
    int i = blockIdx.x * 256 + threadIdx.x;   // 256*1152 = 294912 exact
    int k = i / KK;
    int r = i - k * KK;
    int tap = r >> 7;          // 0..8
    int c = r & 127;
    wt[i] = quant_bf16(w[(size_t)(k * CIN + c) * 9 + tap]);
}

// ---- main implicit GEMM ----------------------------------------------------
// LDS: ldsA[buf][half][128*64] bf16 (buf0 = even kt, buf1 = odd kt), same B.
// Row = 128B = 8 chunks of 16B; slot s at row r holds data chunk s^(r&7)
// (staged via pre-swizzled GLOBAL source, gload_lds dest stays linear).
//
// Iteration it: compute kt=2it (buf0, phases 0-3) and kt=2it+1 (buf1, 4-7).
//   p0: read A(q4=0)+B(ch=0) of buf0                 -> MFMA quad (0,0)
//   p1: read B(ch=1)                                 -> MFMA quad (0,1)
//   p2: read A(q4=1)                                 -> MFMA quad (1,0)
//   p3: stage kt+2 -> buf0 (8 gloads), vmcnt(8)      -> MFMA quad (1,1)
//   p4-p7: same on buf1; p7 stages kt+3 -> buf1, vmcnt(8)
// vmcnt(8) = only the 8 just-issued staging loads may remain in flight, so
// the buffer read 1 phase later is proven landed. Never vmcnt(0) in-loop.
// Buffer safety: buf0 reads all complete by p2's post-MFMA barrier (p3 reads
// nothing), so p3's overwrite of buf0 is ordered; same for buf1 at p7.

#define GLOAD(gsrc, ldst)                                                      \
    __builtin_amdgcn_global_load_lds(                                          \
        (__attribute__((address_space(1))) void*)(void*)(gsrc),                \
        (__attribute__((address_space(3))) void*)(void*)(ldst), 16, 0, 0)

#define STAGE_A(bsel, kt) do {                                                 \
    GLOAD(aGp[0][0] + (size_t)(kt) * 64, &ldsA[bsel][0][(wv * 8) * 64]);       \
    GLOAD(aGp[0][1] + (size_t)(kt) * 64, &ldsA[bsel][0][(64 + wv * 8) * 64]);  \
    GLOAD(aGp[1][0] + (size_t)(kt) * 64, &ldsA[bsel][1][(wv * 8) * 64]);       \
    GLOAD(aGp[1][1] + (size_t)(kt) * 64, &ldsA[bsel][1][(64 + wv * 8) * 64]);  \
} while (0)

#define STAGE_B(bsel, kt) do {                                                 \
    const int tap_ = (kt) >> 1;                                                \
    const size_t boff_ = (size_t)((tap_ / 3) * HP + (tap_ % 3)) * CIN          \
                       + (size_t)((kt) & 1) * 64;                              \
    GLOAD(bGp[0][0] + boff_, &ldsB[bsel][0][(wv * 8) * 64]);                   \
    GLOAD(bGp[0][1] + boff_, &ldsB[bsel][0][(64 + wv * 8) * 64]);              \
    GLOAD(bGp[1][0] + boff_, &ldsB[bsel][1][(wv * 8) * 64]);                   \
    GLOAD(bGp[1][1] + boff_, &ldsB[bsel][1][(64 + wv * 8) * 64]);              \
} while (0)

#define READ_A(bsel, q4) do {                                                  \
    _Pragma("unroll")                                                          \
    for (int f_ = 0; f_ < 4; ++f_) {                                           \
        const int r_ = (q4) * 64 + f_ * 16 + m16;                              \
        ra[f_][0] = *(const short8*)&ldsA[bsel][wm][r_ * 64 + sl0];            \
        ra[f_][1] = *(const short8*)&ldsA[bsel][wm][r_ * 64 + sl1];            \
    }                                                                          \
} while (0)

#define READ_B(dst, bsel, ch) do {                                             \
    _Pragma("unroll")                                                          \
    for (int fc_ = 0; fc_ < 2; ++fc_) {                                        \
        const int r_ = bl + (ch) * 32 + fc_ * 16 + m16;                        \
        dst[fc_][0] = *(const short8*)&ldsB[bsel][bh][r_ * 64 + sl0];          \
        dst[fc_][1] = *(const short8*)&ldsB[bsel][bh][r_ * 64 + sl1];          \
    }                                                                          \
} while (0)

#define MFMA_Q(q4, ch, B) do {                                                 \
    _Pragma("unroll")                                                          \
    for (int s_ = 0; s_ < 2; ++s_)                                             \
    _Pragma("unroll")                                                          \
    for (int f_ = 0; f_ < 4; ++f_)                                             \
    _Pragma("unroll")                                                          \
    for (int c_ = 0; c_ < 2; ++c_)                                             \
        acc[q4][f_][ch][c_] = __builtin_amdgcn_mfma_f32_16x16x32_bf16(         \
            ra[f_][s_], B[c_][s_], acc[q4][f_][ch][c_], 0, 0, 0);              \
} while (0)

#define PHASE_TAIL(...) do {                                                   \
    __builtin_amdgcn_s_barrier();                                              \
    asm volatile("s_waitcnt lgkmcnt(0)" ::: "memory");                         \
    __builtin_amdgcn_sched_barrier(0);                                         \
    __builtin_amdgcn_s_setprio(1);                                             \
    __VA_ARGS__;                                                               \
    __builtin_amdgcn_s_setprio(0);                                             \
    __builtin_amdgcn_s_barrier();                                              \
} while (0)

__global__ __launch_bounds__(512, 2) void conv_gemm(const uint16_t* __restrict__ xp,
                                                    const uint16_t* __restrict__ wt,
                                                    float* __restrict__ out) {
    __shared__ __align__(16) uint16_t ldsA[2][2][128 * 64];   // 64 KiB
    __shared__ __align__(16) uint16_t ldsB[2][2][128 * 64];   // 64 KiB

    const int tid  = threadIdx.x;
    const int l    = tid & 63;
    const int wv   = tid >> 6;        // 0..7
    const int wm   = wv >> 2;         // 0..1: kout half (wave reads A-half wm)
    const int wn   = wv & 3;          // 0..3: px quarter
    const int bh   = wn >> 1;         // B half this wave reads
    const int bl   = (wn & 1) * 64;   // local px base within B half
    const int srow = l >> 3;          // 0..7
    const int c_data = (l & 7) ^ srow;    // swizzled source chunk
    const int m16  = l & 15;
    const int q    = l >> 4;          // 0..3
    const int r7   = m16 & 7;
    const int sl0  = ((0 + q) ^ r7) * 8;  // read slot, k-half 0 (elements)
    const int sl1  = ((4 + q) ^ r7) * 8;  // read slot, k-half 1

    const int b = blockIdx.x;                      // 0..391
    const int pxblk = (b & 7) * 49 + (b >> 3);     // XCD swizzle, 392 = 8*49

    // Per-lane global staging base pointers (fixed across K loop).
    const uint16_t* aGp[2][2];
    const uint16_t* bGp[2][2];
#pragma unroll
    for (int h_ = 0; h_ < 2; ++h_)
#pragma unroll
        for (int j_ = 0; j_ < 2; ++j_) {
            const int row = h_ * 128 + j_ * 64 + wv * 8 + srow;   // 0..255
            aGp[h_][j_] = wt + (size_t)row * KK + c_data * 8;
            const int p = pxblk * 256 + row;                      // global px
            const int n = p / 3136; const int rem = p - n * 3136;
            const int hh = rem / HW; const int ww = rem - hh * HW;
            bGp[h_][j_] = xp + (size_t)((n * HP + hh) * HP + ww) * CIN + c_data * 8;
        }

    floatx4 acc[2][4][2][2];
#pragma unroll
    for (int a_ = 0; a_ < 2; ++a_)
#pragma unroll
        for (int f_ = 0; f_ < 4; ++f_)
#pragma unroll
            for (int c_ = 0; c_ < 2; ++c_)
#pragma unroll
                for (int d_ = 0; d_ < 2; ++d_)
                    acc[a_][f_][c_][d_] = (floatx4){0.f, 0.f, 0.f, 0.f};

    short8 ra[4][2];          // A frags for the active row-half (q4)
    short8 rb0[2][2];         // B frags ch=0
    short8 rb1[2][2];         // B frags ch=1

    // ---- prologue: stage kt0 -> buf0, kt1 -> buf1; only kt1 may stay in flight
    STAGE_A(0, 0); STAGE_B(0, 0);
    STAGE_A(1, 1); STAGE_B(1, 1);
    asm volatile("s_waitcnt vmcnt(8)" ::: "memory");
    __builtin_amdgcn_s_barrier();

#pragma unroll 1
    for (int it = 0; it < 8; ++it) {
        const int ktE = 2 * it + 2;
        const int ktO = 2 * it + 3;
        // ---- kt even (buf0)
        READ_A(0, 0);
        READ_B(rb0, 0, 0);
        PHASE_TAIL(MFMA_Q(0, 0, rb0));                  // p0
        READ_B(rb1, 0, 1);
        PHASE_TAIL(MFMA_Q(0, 1, rb1));                  // p1
        READ_A(0, 1);
        PHASE_TAIL(MFMA_Q(1, 0, rb0));                  // p2
        STAGE_A(0, ktE); STAGE_B(0, ktE);               // buf0 free since p2 end
        asm volatile("s_waitcnt vmcnt(8)" ::: "memory"); // drains buf1 (kt 2it+1)
        PHASE_TAIL(MFMA_Q(1, 1, rb1));                  // p3
        // ---- kt odd (buf1)
        READ_A(1, 0);
        READ_B(rb0, 1, 0);
        PHASE_TAIL(MFMA_Q(0, 0, rb0));                  // p4
        READ_B(rb1, 1, 1);
        PHASE_TAIL(MFMA_Q(0, 1, rb1));                  // p5
        READ_A(1, 1);
        PHASE_TAIL(MFMA_Q(1, 0, rb0));                  // p6
        STAGE_A(1, ktO); STAGE_B(1, ktO);               // buf1 free since p6 end
        asm volatile("s_waitcnt vmcnt(8)" ::: "memory"); // drains buf0 (kt 2it+2)
        PHASE_TAIL(MFMA_Q(1, 1, rb1));                  // p7
    }

    // ---- trailing iteration (kt16 buf0, kt17 buf1): no staging
    READ_A(0, 0);
    READ_B(rb0, 0, 0);
    PHASE_TAIL(MFMA_Q(0, 0, rb0));
    READ_B(rb1, 0, 1);
    PHASE_TAIL(MFMA_Q(0, 1, rb1));
    READ_A(0, 1);
    PHASE_TAIL(MFMA_Q(1, 0, rb0));
    asm volatile("s_waitcnt vmcnt(0)" ::: "memory");    // kt17 fully landed
    PHASE_TAIL(MFMA_Q(1, 1, rb1));
    READ_A(1, 0);
    READ_B(rb0, 1, 0);
    PHASE_TAIL(MFMA_Q(0, 0, rb0));
    READ_B(rb1, 1, 1);
    PHASE_TAIL(MFMA_Q(0, 1, rb1));
    READ_A(1, 1);
    PHASE_TAIL(MFMA_Q(1, 0, rb0));
    PHASE_TAIL(MFMA_Q(1, 1, rb1));

    // ---- epilogue: D row = kout (quad*4+reg), col = px (lane&15)
#pragma unroll
    for (int ch = 0; ch < 2; ++ch)
#pragma unroll
        for (int fc = 0; fc < 2; ++fc) {
            const int p = pxblk * 256 + wn * 64 + ch * 32 + fc * 16 + m16;
            const int n = p / 3136; const int rem = p - n * 3136;
            float* op = out + (size_t)(n * KOUT + wm * 128) * 3136 + rem;
#pragma unroll
            for (int q4 = 0; q4 < 2; ++q4)
#pragma unroll
                for (int f = 0; f < 4; ++f) {
                    const int kl = q4 * 64 + f * 16 + q * 4;
#pragma unroll
                    for (int t = 0; t < 4; ++t)
                        op[(size_t)(kl + t) * 3136] = acc[q4][f][ch][fc][t];
                }
        }
}

extern "C" void kernel_launch(void* const* d_in, const int* in_sizes, int n_in,
                              void* d_out, int out_size, void* d_ws, size_t ws_size,
                              hipStream_t stream) {
    const float* x = (const float*)d_in[0];
    const float* w = (const float*)d_in[1];
    float* out = (float*)d_out;

    uint16_t* xp  = (uint16_t*)d_ws;                           // 27.56 MB padded bf16 x
    uint16_t* wtb = (uint16_t*)((char*)d_ws + WT_OFF_BYTES);   // 0.59 MB bf16 weights

    quant_pad_x<<<NIMG * HP, 256, 0, stream>>>(x, xp);         // covers ALL of xp incl. borders
    quant_w<<<(KOUT * KK) / 256, 256, 0, stream>>>(w, wtb);

    conv_gemm<<<dim3(392), dim3(512), 0, stream>>>(xp, wtb, out);
}

// Round 2
// 217.733 us; speedup vs baseline: 1.0104x; 1.0104x over previous
//
#include <hip/hip_runtime.h>
#include <cstdint>
#include <cstddef>

// ---------------------------------------------------------------------------
// Conv2d 3x3 s1 p1 on 16-bit fixed-point (12 frac bits) quantized operands.
// x: (32,128,56,56) f32   w: (256,128,3,3) f32   out: (32,256,56,56) f32
// Implicit GEMM M=256, N=100352, K=1152.
// 256x256 tile, BK=64, 512 thr / 8 waves, 8-phase schedule with counted vmcnt
// (T3+T4) + setprio (T5), XOR-8 chunk swizzle, XCD swizzle (392 = 8*49).
// R1 fix: removed per-phase sched_barrier(0) (m141 order-pinning regression);
// compiler now free to interleave lgkmcnt waits with the MFMA cluster.
// Epilogue reordered so both 64B half-lines of each 128B line issue adjacent.
// ---------------------------------------------------------------------------

typedef __attribute__((ext_vector_type(8))) short short8;
typedef __attribute__((ext_vector_type(4))) float floatx4;

#define NIMG 32
#define CIN  128
#define HW   56
#define KOUT 256
#define HP   58                                   // padded H/W
#define XPAD_ELEMS ((size_t)NIMG * HP * HP * CIN) // 13,778,944
#define WT_OFF_BYTES (XPAD_ELEMS * 2)             // 27,557,888 (256B aligned)
#define KK 1152

__device__ __forceinline__ uint16_t quant_bf16(float v) {
    // round-half-even to 12 frac bits, clip to int16 range, then RNE to bf16
    float q = rintf(v * 4096.0f);
    q = fminf(fmaxf(q, -32768.0f), 32767.0f) * (1.0f / 4096.0f);
    union { float f; uint32_t u; } cv; cv.f = q;
    uint32_t u = cv.u;
    return (uint16_t)((u + 0x7fffu + ((u >> 16) & 1u)) >> 16);
}

// ---- transform x: NCHW f32 -> padded NHWC bf16 [32][58][58][128] ----------
__global__ __launch_bounds__(256) void quant_pad_x(const float* __restrict__ x,
                                                   uint16_t* __restrict__ xp) {
    const int b = blockIdx.x;            // one padded row (n, hp) each
    const int n = b / HP, hp = b - n * HP;
    uint16_t* row = xp + (size_t)(n * HP + hp) * HP * CIN;

    if (hp == 0 || hp == HP - 1) {       // top/bottom pad row: all zeros
        uint4 z{0, 0, 0, 0};
        uint4* d = (uint4*)row;
        for (int t = threadIdx.x; t < HP * CIN * 2 / 16; t += 256) d[t] = z;
        return;
    }
    const int h = hp - 1;
    __shared__ uint16_t tile[HW * 130];  // [w][c], +2 pad breaks bank conflicts
    const float* src = x + (size_t)n * CIN * HW * HW + (size_t)h * HW;
    for (int t = threadIdx.x; t < CIN * 14; t += 256) {      // float4 loads
        int c = t / 14, w4 = t - c * 14;
        float4 v = *(const float4*)(src + (size_t)c * (HW * HW) + w4 * 4);
        int base = (w4 * 4) * 130 + c;
        tile[base]       = quant_bf16(v.x);
        tile[base + 130] = quant_bf16(v.y);
        tile[base + 260] = quant_bf16(v.z);
        tile[base + 390] = quant_bf16(v.w);
    }
    __syncthreads();
    if (threadIdx.x < 32) {              // zero left/right pad pixels
        uint4 z{0, 0, 0, 0};
        if (threadIdx.x < 16) ((uint4*)row)[threadIdx.x] = z;
        else ((uint4*)(row + 57 * CIN))[threadIdx.x - 16] = z;
    }
    uint2* dst = (uint2*)(row + CIN);    // interior cols 1..56, 8B stores
    for (int t = threadIdx.x; t < (HW * CIN) / 4; t += 256) {
        int w = t >> 5, c4 = (t & 31) * 4;
        uint32_t a = tile[w * 130 + c4]     | ((uint32_t)tile[w * 130 + c4 + 1] << 16);
        uint32_t c = tile[w * 130 + c4 + 2] | ((uint32_t)tile[w * 130 + c4 + 3] << 16);
        dst[t] = make_uint2(a, c);
    }
}

// ---- transform w: OIHW f32 -> Wt[k][tap*128+c] bf16 ------------------------
__global__ __launch_bounds__(256) void quant_w(const float* __restrict__ w,
                                               uint16_t* __restrict__ wt) {
    int i = blockIdx.x * 256 + threadIdx.x;   // 256*1152 = 294912 exact
    int k = i / KK;
    int r = i - k * KK;
    int tap = r >> 7;          // 0..8
    int c = r & 127;
    wt[i] = quant_bf16(w[(size_t)(k * CIN + c) * 9 + tap]);
}

// ---- main implicit GEMM ----------------------------------------------------
// LDS: ldsA[buf][half][128*64] bf16 (buf0 = even kt, buf1 = odd kt), same B.
// Row = 128B = 8 chunks of 16B; slot s at row r holds data chunk s^(r&7)
// (staged via pre-swizzled GLOBAL source, gload_lds dest stays linear).
//
// Iteration it: compute kt=2it (buf0, phases 0-3) and kt=2it+1 (buf1, 4-7).
//   p0: read A(q4=0)+B(ch=0) of buf0                 -> MFMA quad (0,0)
//   p1: read B(ch=1)                                 -> MFMA quad (0,1)
//   p2: read A(q4=1)                                 -> MFMA quad (1,0)
//   p3: stage kt+2 -> buf0 (8 gloads), vmcnt(8)      -> MFMA quad (1,1)
//   p4-p7: same on buf1; p7 stages kt+3 -> buf1, vmcnt(8)
// vmcnt(8) = only the 8 just-issued staging loads may remain in flight, so
// the buffer read 1 phase later is proven landed. Never vmcnt(0) in-loop.
// Buffer safety: buf0 reads all complete by p2's post-MFMA barrier (p3 reads
// nothing), so p3's overwrite of buf0 is ordered; same for buf1 at p7.

#define GLOAD(gsrc, ldst)                                                      \
    __builtin_amdgcn_global_load_lds(                                          \
        (__attribute__((address_space(1))) void*)(void*)(gsrc),                \
        (__attribute__((address_space(3))) void*)(void*)(ldst), 16, 0, 0)

#define STAGE_A(bsel, kt) do {                                                 \
    GLOAD(aGp[0][0] + (size_t)(kt) * 64, &ldsA[bsel][0][(wv * 8) * 64]);       \
    GLOAD(aGp[0][1] + (size_t)(kt) * 64, &ldsA[bsel][0][(64 + wv * 8) * 64]);  \
    GLOAD(aGp[1][0] + (size_t)(kt) * 64, &ldsA[bsel][1][(wv * 8) * 64]);       \
    GLOAD(aGp[1][1] + (size_t)(kt) * 64, &ldsA[bsel][1][(64 + wv * 8) * 64]);  \
} while (0)

#define STAGE_B(bsel, kt) do {                                                 \
    const int tap_ = (kt) >> 1;                                                \
    const size_t boff_ = (size_t)((tap_ / 3) * HP + (tap_ % 3)) * CIN          \
                       + (size_t)((kt) & 1) * 64;                              \
    GLOAD(bGp[0][0] + boff_, &ldsB[bsel][0][(wv * 8) * 64]);                   \
    GLOAD(bGp[0][1] + boff_, &ldsB[bsel][0][(64 + wv * 8) * 64]);              \
    GLOAD(bGp[1][0] + boff_, &ldsB[bsel][1][(wv * 8) * 64]);                   \
    GLOAD(bGp[1][1] + boff_, &ldsB[bsel][1][(64 + wv * 8) * 64]);              \
} while (0)

#define READ_A(bsel, q4) do {                                                  \
    _Pragma("unroll")                                                          \
    for (int f_ = 0; f_ < 4; ++f_) {                                           \
        const int r_ = (q4) * 64 + f_ * 16 + m16;                              \
        ra[f_][0] = *(const short8*)&ldsA[bsel][wm][r_ * 64 + sl0];            \
        ra[f_][1] = *(const short8*)&ldsA[bsel][wm][r_ * 64 + sl1];            \
    }                                                                          \
} while (0)

#define READ_B(dst, bsel, ch) do {                                             \
    _Pragma("unroll")                                                          \
    for (int fc_ = 0; fc_ < 2; ++fc_) {                                        \
        const int r_ = bl + (ch) * 32 + fc_ * 16 + m16;                        \
        dst[fc_][0] = *(const short8*)&ldsB[bsel][bh][r_ * 64 + sl0];          \
        dst[fc_][1] = *(const short8*)&ldsB[bsel][bh][r_ * 64 + sl1];          \
    }                                                                          \
} while (0)

#define MFMA_Q(q4, ch, B) do {                                                 \
    _Pragma("unroll")                                                          \
    for (int s_ = 0; s_ < 2; ++s_)                                             \
    _Pragma("unroll")                                                          \
    for (int f_ = 0; f_ < 4; ++f_)                                             \
    _Pragma("unroll")                                                          \
    for (int c_ = 0; c_ < 2; ++c_)                                             \
        acc[q4][f_][ch][c_] = __builtin_amdgcn_mfma_f32_16x16x32_bf16(         \
            ra[f_][s_], B[c_][s_], acc[q4][f_][ch][c_], 0, 0, 0);              \
} while (0)

// R1: no sched_barrier(0) here. ds_reads are C++ loads (deps compiler-tracked)
// so MFMA may legally hoist past the asm lgkmcnt(0) -> fine-grained lgkm waits.
#define PHASE_TAIL(...) do {                                                   \
    __builtin_amdgcn_s_barrier();                                              \
    asm volatile("s_waitcnt lgkmcnt(0)" ::: "memory");                         \
    __builtin_amdgcn_s_setprio(1);                                             \
    __VA_ARGS__;                                                               \
    __builtin_amdgcn_s_setprio(0);                                             \
    __builtin_amdgcn_s_barrier();                                              \
} while (0)

__global__ __launch_bounds__(512, 2) void conv_gemm(const uint16_t* __restrict__ xp,
                                                    const uint16_t* __restrict__ wt,
                                                    float* __restrict__ out) {
    __shared__ __align__(16) uint16_t ldsA[2][2][128 * 64];   // 64 KiB
    __shared__ __align__(16) uint16_t ldsB[2][2][128 * 64];   // 64 KiB

    const int tid  = threadIdx.x;
    const int l    = tid & 63;
    const int wv   = tid >> 6;        // 0..7
    const int wm   = wv >> 2;         // 0..1: kout half (wave reads A-half wm)
    const int wn   = wv & 3;          // 0..3: px quarter
    const int bh   = wn >> 1;         // B half this wave reads
    const int bl   = (wn & 1) * 64;   // local px base within B half
    const int srow = l >> 3;          // 0..7
    const int c_data = (l & 7) ^ srow;    // swizzled source chunk
    const int m16  = l & 15;
    const int q    = l >> 4;          // 0..3
    const int r7   = m16 & 7;
    const int sl0  = ((0 + q) ^ r7) * 8;  // read slot, k-half 0 (elements)
    const int sl1  = ((4 + q) ^ r7) * 8;  // read slot, k-half 1

    const int b = blockIdx.x;                      // 0..391
    const int pxblk = (b & 7) * 49 + (b >> 3);     // XCD swizzle, 392 = 8*49

    // Per-lane global staging base pointers (fixed across K loop).
    const uint16_t* aGp[2][2];
    const uint16_t* bGp[2][2];
#pragma unroll
    for (int h_ = 0; h_ < 2; ++h_)
#pragma unroll
        for (int j_ = 0; j_ < 2; ++j_) {
            const int row = h_ * 128 + j_ * 64 + wv * 8 + srow;   // 0..255
            aGp[h_][j_] = wt + (size_t)row * KK + c_data * 8;
            const int p = pxblk * 256 + row;                      // global px
            const int n = p / 3136; const int rem = p - n * 3136;
            const int hh = rem / HW; const int ww = rem - hh * HW;
            bGp[h_][j_] = xp + (size_t)((n * HP + hh) * HP + ww) * CIN + c_data * 8;
        }

    floatx4 acc[2][4][2][2];
#pragma unroll
    for (int a_ = 0; a_ < 2; ++a_)
#pragma unroll
        for (int f_ = 0; f_ < 4; ++f_)
#pragma unroll
            for (int c_ = 0; c_ < 2; ++c_)
#pragma unroll
                for (int d_ = 0; d_ < 2; ++d_)
                    acc[a_][f_][c_][d_] = (floatx4){0.f, 0.f, 0.f, 0.f};

    short8 ra[4][2];          // A frags for the active row-half (q4)
    short8 rb0[2][2];         // B frags ch=0
    short8 rb1[2][2];         // B frags ch=1

    // ---- prologue: stage kt0 -> buf0, kt1 -> buf1; only kt1 may stay in flight
    STAGE_A(0, 0); STAGE_B(0, 0);
    STAGE_A(1, 1); STAGE_B(1, 1);
    asm volatile("s_waitcnt vmcnt(8)" ::: "memory");
    __builtin_amdgcn_s_barrier();

#pragma unroll 1
    for (int it = 0; it < 8; ++it) {
        const int ktE = 2 * it + 2;
        const int ktO = 2 * it + 3;
        // ---- kt even (buf0)
        READ_A(0, 0);
        READ_B(rb0, 0, 0);
        PHASE_TAIL(MFMA_Q(0, 0, rb0));                  // p0
        READ_B(rb1, 0, 1);
        PHASE_TAIL(MFMA_Q(0, 1, rb1));                  // p1
        READ_A(0, 1);
        PHASE_TAIL(MFMA_Q(1, 0, rb0));                  // p2
        STAGE_A(0, ktE); STAGE_B(0, ktE);               // buf0 free since p2 end
        asm volatile("s_waitcnt vmcnt(8)" ::: "memory"); // drains buf1 (kt 2it+1)
        PHASE_TAIL(MFMA_Q(1, 1, rb1));                  // p3
        // ---- kt odd (buf1)
        READ_A(1, 0);
        READ_B(rb0, 1, 0);
        PHASE_TAIL(MFMA_Q(0, 0, rb0));                  // p4
        READ_B(rb1, 1, 1);
        PHASE_TAIL(MFMA_Q(0, 1, rb1));                  // p5
        READ_A(1, 1);
        PHASE_TAIL(MFMA_Q(1, 0, rb0));                  // p6
        STAGE_A(1, ktO); STAGE_B(1, ktO);               // buf1 free since p6 end
        asm volatile("s_waitcnt vmcnt(8)" ::: "memory"); // drains buf0 (kt 2it+2)
        PHASE_TAIL(MFMA_Q(1, 1, rb1));                  // p7
    }

    // ---- trailing iteration (kt16 buf0, kt17 buf1): no staging
    READ_A(0, 0);
    READ_B(rb0, 0, 0);
    PHASE_TAIL(MFMA_Q(0, 0, rb0));
    READ_B(rb1, 0, 1);
    PHASE_TAIL(MFMA_Q(0, 1, rb1));
    READ_A(0, 1);
    PHASE_TAIL(MFMA_Q(1, 0, rb0));
    asm volatile("s_waitcnt vmcnt(0)" ::: "memory");    // kt17 fully landed
    PHASE_TAIL(MFMA_Q(1, 1, rb1));
    READ_A(1, 0);
    READ_B(rb0, 1, 0);
    PHASE_TAIL(MFMA_Q(0, 0, rb0));
    READ_B(rb1, 1, 1);
    PHASE_TAIL(MFMA_Q(0, 1, rb1));
    READ_A(1, 1);
    PHASE_TAIL(MFMA_Q(1, 0, rb0));
    PHASE_TAIL(MFMA_Q(1, 1, rb1));

    // ---- epilogue: D row = kout (quad*4+reg), col = px (lane&15).
    // fc (the two 64B halves of each 128B line) innermost so the line is
    // completed by adjacent store instructions (write-combine friendly).
#pragma unroll
    for (int ch = 0; ch < 2; ++ch) {
        const int p0 = pxblk * 256 + wn * 64 + ch * 32 + m16;
        const int n = p0 / 3136; const int rem0 = p0 - n * 3136;   // fc=0 px
        // px p0 and p0+16 stay within the same image: pxblk*256 is a multiple
        // of 32 and 3136 % 32 == 0, so the 32-px group never straddles n.
        float* opb = out + (size_t)(n * KOUT + wm * 128) * 3136 + rem0;
#pragma unroll
        for (int q4 = 0; q4 < 2; ++q4)
#pragma unroll
            for (int f = 0; f < 4; ++f) {
                const int kl = q4 * 64 + f * 16 + q * 4;
#pragma unroll
                for (int t = 0; t < 4; ++t) {
                    float* op = opb + (size_t)(kl + t) * 3136;
                    op[0]  = acc[q4][f][ch][0][t];
                    op[16] = acc[q4][f][ch][1][t];
                }
            }
    }
}

extern "C" void kernel_launch(void* const* d_in, const int* in_sizes, int n_in,
                              void* d_out, int out_size, void* d_ws, size_t ws_size,
                              hipStream_t stream) {
    const float* x = (const float*)d_in[0];
    const float* w = (const float*)d_in[1];
    float* out = (float*)d_out;

    uint16_t* xp  = (uint16_t*)d_ws;                           // 27.56 MB padded bf16 x
    uint16_t* wtb = (uint16_t*)((char*)d_ws + WT_OFF_BYTES);   // 0.59 MB bf16 weights

    quant_pad_x<<<NIMG * HP, 256, 0, stream>>>(x, xp);         // covers ALL of xp incl. borders
    quant_w<<<(KOUT * KK) / 256, 256, 0, stream>>>(w, wtb);

    conv_gemm<<<dim3(392), dim3(512), 0, stream>>>(xp, wtb, out);
}

// Round 3
// 212.729 us; speedup vs baseline: 1.0342x; 1.0235x over previous
//
#include <hip/hip_runtime.h>
#include <cstdint>
#include <cstddef>

// ---------------------------------------------------------------------------
// Conv2d 3x3 s1 p1 on 16-bit fixed-point (12 frac bits) quantized operands.
// x: (32,128,56,56) f32   w: (256,128,3,3) f32   out: (32,256,56,56) f32
// Implicit GEMM M=256, N=100352, K=1152.
// 256x256 tile, BK=64, 512 thr / 8 waves, XOR-8 chunk swizzle, XCD swizzle.
// R2: COARSE sync — 2 barriers per K-step (was 8). Whole-kt body is straight-
// line; compiler does fine-grained lgkmcnt interleave of ds_read vs MFMA, and
// the 2 waves/SIMD drift to overlap LDS-port and MFMA-pipe (m114 mechanism).
// Counted vmcnt(8) kept: staging loads stay in flight across a full K-step.
// ---------------------------------------------------------------------------

typedef __attribute__((ext_vector_type(8))) short short8;
typedef __attribute__((ext_vector_type(4))) float floatx4;

#define NIMG 32
#define CIN  128
#define HW   56
#define KOUT 256
#define HP   58                                   // padded H/W
#define XPAD_ELEMS ((size_t)NIMG * HP * HP * CIN) // 13,778,944
#define WT_OFF_BYTES (XPAD_ELEMS * 2)             // 27,557,888 (256B aligned)
#define KK 1152

__device__ __forceinline__ uint16_t quant_bf16(float v) {
    // round-half-even to 12 frac bits, clip to int16 range, then RNE to bf16
    float q = rintf(v * 4096.0f);
    q = fminf(fmaxf(q, -32768.0f), 32767.0f) * (1.0f / 4096.0f);
    union { float f; uint32_t u; } cv; cv.f = q;
    uint32_t u = cv.u;
    return (uint16_t)((u + 0x7fffu + ((u >> 16) & 1u)) >> 16);
}

// ---- transform x: NCHW f32 -> padded NHWC bf16 [32][58][58][128] ----------
__global__ __launch_bounds__(256) void quant_pad_x(const float* __restrict__ x,
                                                   uint16_t* __restrict__ xp) {
    const int b = blockIdx.x;            // one padded row (n, hp) each
    const int n = b / HP, hp = b - n * HP;
    uint16_t* row = xp + (size_t)(n * HP + hp) * HP * CIN;

    if (hp == 0 || hp == HP - 1) {       // top/bottom pad row: all zeros
        uint4 z{0, 0, 0, 0};
        uint4* d = (uint4*)row;
        for (int t = threadIdx.x; t < HP * CIN * 2 / 16; t += 256) d[t] = z;
        return;
    }
    const int h = hp - 1;
    __shared__ uint16_t tile[HW * 130];  // [w][c], +2 pad breaks bank conflicts
    const float* src = x + (size_t)n * CIN * HW * HW + (size_t)h * HW;
    for (int t = threadIdx.x; t < CIN * 14; t += 256) {      // float4 loads
        int c = t / 14, w4 = t - c * 14;
        float4 v = *(const float4*)(src + (size_t)c * (HW * HW) + w4 * 4);
        int base = (w4 * 4) * 130 + c;
        tile[base]       = quant_bf16(v.x);
        tile[base + 130] = quant_bf16(v.y);
        tile[base + 260] = quant_bf16(v.z);
        tile[base + 390] = quant_bf16(v.w);
    }
    __syncthreads();
    if (threadIdx.x < 32) {              // zero left/right pad pixels
        uint4 z{0, 0, 0, 0};
        if (threadIdx.x < 16) ((uint4*)row)[threadIdx.x] = z;
        else ((uint4*)(row + 57 * CIN))[threadIdx.x - 16] = z;
    }
    uint2* dst = (uint2*)(row + CIN);    // interior cols 1..56, 8B stores
    for (int t = threadIdx.x; t < (HW * CIN) / 4; t += 256) {
        int w = t >> 5, c4 = (t & 31) * 4;
        uint32_t a = tile[w * 130 + c4]     | ((uint32_t)tile[w * 130 + c4 + 1] << 16);
        uint32_t c = tile[w * 130 + c4 + 2] | ((uint32_t)tile[w * 130 + c4 + 3] << 16);
        dst[t] = make_uint2(a, c);
    }
}

// ---- transform w: OIHW f32 -> Wt[k][tap*128+c] bf16 ------------------------
__global__ __launch_bounds__(256) void quant_w(const float* __restrict__ w,
                                               uint16_t* __restrict__ wt) {
    int i = blockIdx.x * 256 + threadIdx.x;   // 256*1152 = 294912 exact
    int k = i / KK;
    int r = i - k * KK;
    int tap = r >> 7;          // 0..8
    int c = r & 127;
    wt[i] = quant_bf16(w[(size_t)(k * CIN + c) * 9 + tap]);
}

// ---- main implicit GEMM ----------------------------------------------------
// LDS: ldsA/ldsB[buf][half][128*64] bf16 (buf0 = even kt, buf1 = odd kt).
// Row = 128B = 8 chunks of 16B; slot s at row r holds data chunk s^(r&7)
// (staged via pre-swizzled GLOBAL source, gload_lds dest stays linear).
//
// Per K-step kt (buffer stable, no internal barriers):
//   reads ra(q4=0), rb0, rb1  (16 ds_read_b128)
//   MFMA quads (0,0), (0,1)
//   reads ra(q4=1)            (8 ds_read_b128, WAR-reuse of ra regs)
//   MFMA quads (1,0), (1,1)
//   barrier                   // all waves done READING this buffer
//   STAGE kt+2 into it        (8 global_load_lds)
//   vmcnt(8)                  // kt+1's loads (issued one full kt ago) landed
//   barrier                   // kt+1 buffer visible to all waves
// Never a fresh-drain vmcnt in the loop; staging spans an entire K-step.

#define GLOAD(gsrc, ldst)                                                      \
    __builtin_amdgcn_global_load_lds(                                          \
        (__attribute__((address_space(1))) void*)(void*)(gsrc),                \
        (__attribute__((address_space(3))) void*)(void*)(ldst), 16, 0, 0)

#define STAGE_A(bsel, kt) do {                                                 \
    GLOAD(aGp[0][0] + (size_t)(kt) * 64, &ldsA[bsel][0][(wv * 8) * 64]);       \
    GLOAD(aGp[0][1] + (size_t)(kt) * 64, &ldsA[bsel][0][(64 + wv * 8) * 64]);  \
    GLOAD(aGp[1][0] + (size_t)(kt) * 64, &ldsA[bsel][1][(wv * 8) * 64]);       \
    GLOAD(aGp[1][1] + (size_t)(kt) * 64, &ldsA[bsel][1][(64 + wv * 8) * 64]);  \
} while (0)

#define STAGE_B(bsel, kt) do {                                                 \
    const int tap_ = (kt) >> 1;                                                \
    const size_t boff_ = (size_t)((tap_ / 3) * HP + (tap_ % 3)) * CIN          \
                       + (size_t)((kt) & 1) * 64;                              \
    GLOAD(bGp[0][0] + boff_, &ldsB[bsel][0][(wv * 8) * 64]);                   \
    GLOAD(bGp[0][1] + boff_, &ldsB[bsel][0][(64 + wv * 8) * 64]);              \
    GLOAD(bGp[1][0] + boff_, &ldsB[bsel][1][(wv * 8) * 64]);                   \
    GLOAD(bGp[1][1] + boff_, &ldsB[bsel][1][(64 + wv * 8) * 64]);              \
} while (0)

#define READ_A(bsel, q4) do {                                                  \
    _Pragma("unroll")                                                          \
    for (int f_ = 0; f_ < 4; ++f_) {                                           \
        const int r_ = (q4) * 64 + f_ * 16 + m16;                              \
        ra[f_][0] = *(const short8*)&ldsA[bsel][wm][r_ * 64 + sl0];            \
        ra[f_][1] = *(const short8*)&ldsA[bsel][wm][r_ * 64 + sl1];            \
    }                                                                          \
} while (0)

#define READ_B(dst, bsel, ch) do {                                             \
    _Pragma("unroll")                                                          \
    for (int fc_ = 0; fc_ < 2; ++fc_) {                                        \
        const int r_ = bl + (ch) * 32 + fc_ * 16 + m16;                        \
        dst[fc_][0] = *(const short8*)&ldsB[bsel][bh][r_ * 64 + sl0];          \
        dst[fc_][1] = *(const short8*)&ldsB[bsel][bh][r_ * 64 + sl1];          \
    }                                                                          \
} while (0)

#define MFMA_Q(q4, ch, B) do {                                                 \
    _Pragma("unroll")                                                          \
    for (int s_ = 0; s_ < 2; ++s_)                                             \
    _Pragma("unroll")                                                          \
    for (int f_ = 0; f_ < 4; ++f_)                                             \
    _Pragma("unroll")                                                          \
    for (int c_ = 0; c_ < 2; ++c_)                                             \
        acc[q4][f_][ch][c_] = __builtin_amdgcn_mfma_f32_16x16x32_bf16(         \
            ra[f_][s_], B[c_][s_], acc[q4][f_][ch][c_], 0, 0, 0);              \
} while (0)

// One full K-step of compute on buffer bsel. No barriers inside: the compiler
// interleaves ds_read/lgkmcnt with the MFMA clusters (fine-grained waits),
// and co-resident waves drift to overlap LDS port vs matrix pipe.
#define KT_BODY(bsel) do {                                                     \
    READ_A(bsel, 0);                                                           \
    READ_B(rb0, bsel, 0);                                                      \
    READ_B(rb1, bsel, 1);                                                      \
    __builtin_amdgcn_s_setprio(1);                                             \
    MFMA_Q(0, 0, rb0);                                                         \
    MFMA_Q(0, 1, rb1);                                                         \
    __builtin_amdgcn_s_setprio(0);                                             \
    READ_A(bsel, 1);                 /* WAR reuse of ra: after (0,*) issued */  \
    __builtin_amdgcn_s_setprio(1);                                             \
    MFMA_Q(1, 0, rb0);                                                         \
    MFMA_Q(1, 1, rb1);                                                         \
    __builtin_amdgcn_s_setprio(0);                                             \
} while (0)

// End-of-K-step sync + prefetch: overwrite-safety barrier, stage kt+2 into the
// buffer just consumed, counted wait for kt+1 (issued one K-step ago), then
// visibility barrier for kt+1.
#define KT_SYNC_STAGE(bsel, ktn) do {                                          \
    __builtin_amdgcn_s_barrier();                                              \
    STAGE_A(bsel, ktn); STAGE_B(bsel, ktn);                                    \
    asm volatile("s_waitcnt vmcnt(8)" ::: "memory");                           \
    __builtin_amdgcn_s_barrier();                                              \
} while (0)

__global__ __launch_bounds__(512, 2) void conv_gemm(const uint16_t* __restrict__ xp,
                                                    const uint16_t* __restrict__ wt,
                                                    float* __restrict__ out) {
    __shared__ __align__(16) uint16_t ldsA[2][2][128 * 64];   // 64 KiB
    __shared__ __align__(16) uint16_t ldsB[2][2][128 * 64];   // 64 KiB

    const int tid  = threadIdx.x;
    const int l    = tid & 63;
    const int wv   = tid >> 6;        // 0..7
    const int wm   = wv >> 2;         // 0..1: kout half (wave reads A-half wm)
    const int wn   = wv & 3;          // 0..3: px quarter
    const int bh   = wn >> 1;         // B half this wave reads
    const int bl   = (wn & 1) * 64;   // local px base within B half
    const int srow = l >> 3;          // 0..7
    const int c_data = (l & 7) ^ srow;    // swizzled source chunk
    const int m16  = l & 15;
    const int q    = l >> 4;          // 0..3
    const int r7   = m16 & 7;
    const int sl0  = ((0 + q) ^ r7) * 8;  // read slot, k-half 0 (elements)
    const int sl1  = ((4 + q) ^ r7) * 8;  // read slot, k-half 1

    const int b = blockIdx.x;                      // 0..391
    const int pxblk = (b & 7) * 49 + (b >> 3);     // XCD swizzle, 392 = 8*49

    // Per-lane global staging base pointers (fixed across K loop).
    const uint16_t* aGp[2][2];
    const uint16_t* bGp[2][2];
#pragma unroll
    for (int h_ = 0; h_ < 2; ++h_)
#pragma unroll
        for (int j_ = 0; j_ < 2; ++j_) {
            const int row = h_ * 128 + j_ * 64 + wv * 8 + srow;   // 0..255
            aGp[h_][j_] = wt + (size_t)row * KK + c_data * 8;
            const int p = pxblk * 256 + row;                      // global px
            const int n = p / 3136; const int rem = p - n * 3136;
            const int hh = rem / HW; const int ww = rem - hh * HW;
            bGp[h_][j_] = xp + (size_t)((n * HP + hh) * HP + ww) * CIN + c_data * 8;
        }

    floatx4 acc[2][4][2][2];
#pragma unroll
    for (int a_ = 0; a_ < 2; ++a_)
#pragma unroll
        for (int f_ = 0; f_ < 4; ++f_)
#pragma unroll
            for (int c_ = 0; c_ < 2; ++c_)
#pragma unroll
                for (int d_ = 0; d_ < 2; ++d_)
                    acc[a_][f_][c_][d_] = (floatx4){0.f, 0.f, 0.f, 0.f};

    short8 ra[4][2];          // A frags for the active row-half (q4)
    short8 rb0[2][2];         // B frags ch=0
    short8 rb1[2][2];         // B frags ch=1

    // ---- prologue: stage kt0 -> buf0, kt1 -> buf1; only kt1 may stay in flight
    STAGE_A(0, 0); STAGE_B(0, 0);
    STAGE_A(1, 1); STAGE_B(1, 1);
    asm volatile("s_waitcnt vmcnt(8)" ::: "memory");
    __builtin_amdgcn_s_barrier();

#pragma unroll 1
    for (int it = 0; it < 8; ++it) {
        const int ktE = 2 * it + 2;
        const int ktO = 2 * it + 3;
        KT_BODY(0);                     // kt = 2it   (buf0)
        KT_SYNC_STAGE(0, ktE);          // stage kt+2, confirm kt+1
        KT_BODY(1);                     // kt = 2it+1 (buf1)
        KT_SYNC_STAGE(1, ktO);          // stage kt+3, confirm kt+2
    }

    // ---- tail: kt16 (buf0), kt17 (buf1) — no staging
    KT_BODY(0);
    __builtin_amdgcn_s_barrier();
    asm volatile("s_waitcnt vmcnt(0)" ::: "memory");   // kt17 (issued long ago) landed
    __builtin_amdgcn_s_barrier();
    KT_BODY(1);

    // ---- epilogue: D row = kout (quad*4+reg), col = px (lane&15).
    // fc (the two 64B halves of each 128B line) innermost so the line is
    // completed by adjacent store instructions (write-combine friendly).
#pragma unroll
    for (int ch = 0; ch < 2; ++ch) {
        const int p0 = pxblk * 256 + wn * 64 + ch * 32 + m16;
        const int n = p0 / 3136; const int rem0 = p0 - n * 3136;   // fc=0 px
        float* opb = out + (size_t)(n * KOUT + wm * 128) * 3136 + rem0;
#pragma unroll
        for (int q4 = 0; q4 < 2; ++q4)
#pragma unroll
            for (int f = 0; f < 4; ++f) {
                const int kl = q4 * 64 + f * 16 + q * 4;
#pragma unroll
                for (int t = 0; t < 4; ++t) {
                    float* op = opb + (size_t)(kl + t) * 3136;
                    op[0]  = acc[q4][f][ch][0][t];
                    op[16] = acc[q4][f][ch][1][t];
                }
            }
    }
}

extern "C" void kernel_launch(void* const* d_in, const int* in_sizes, int n_in,
                              void* d_out, int out_size, void* d_ws, size_t ws_size,
                              hipStream_t stream) {
    const float* x = (const float*)d_in[0];
    const float* w = (const float*)d_in[1];
    float* out = (float*)d_out;

    uint16_t* xp  = (uint16_t*)d_ws;                           // 27.56 MB padded bf16 x
    uint16_t* wtb = (uint16_t*)((char*)d_ws + WT_OFF_BYTES);   // 0.59 MB bf16 weights

    quant_pad_x<<<NIMG * HP, 256, 0, stream>>>(x, xp);         // covers ALL of xp incl. borders
    quant_w<<<(KOUT * KK) / 256, 256, 0, stream>>>(w, wtb);

    conv_gemm<<<dim3(392), dim3(512), 0, stream>>>(xp, wtb, out);
}